// Round 7
// baseline (212.545 us; speedup 1.0000x reference)
//
#include <hip/hip_runtime.h>
#include <stdint.h>
#include <math.h>

#define D_MODEL 1024
#define NUM_HEADS 16
#define D_K 64
#define SEQ 2048
#define BATCH 2
#define SIM_THRESH 0.7f

#define TS 64          // block tile (square)
#define NROWS (BATCH * SEQ)                       // 4096
#define VP_BLOCKS ((NROWS / TS) * (D_MODEL / TS)) // 64*16 = 1024
#define SIM_ROWB (SEQ / TS)                       // 32
#define SIM_TRI (SIM_ROWB * (SIM_ROWB + 1) / 2)   // 528
#define SIM_BLOCKS (SIM_TRI * BATCH)              // 1056
#define GRID (VP_BLOCKS + SIM_BLOCKS)             // 2080

typedef __attribute__((ext_vector_type(8))) short bf16x8;
typedef __attribute__((ext_vector_type(4))) float f32x4;

static __device__ __forceinline__ unsigned short f2bf(float f) {
    unsigned int u = __float_as_uint(f);
    unsigned int r = (u + 0x7FFF + ((u >> 16) & 1)) >> 16;   // RNE
    return (unsigned short)r;
}
static __device__ __forceinline__ float bf2f(unsigned short u) {
    return __uint_as_float(((unsigned int)u) << 16);
}

// ---------- L1: normalize x rows -> bf16 (+norms, zero cnt)  AND  cast Wv -> bf16 ----------
__global__ __launch_bounds__(256) void k_prep(const float* __restrict__ x,
                                              const float* __restrict__ Wv,
                                              unsigned short* __restrict__ xn,
                                              unsigned short* __restrict__ Wvb,
                                              float* __restrict__ norms,
                                              int* __restrict__ cnt) {
    int bid = blockIdx.x, tid = threadIdx.x;
    if (bid < NROWS) {
        const float4* xr = (const float4*)(x + (size_t)bid * D_MODEL);
        float4 vv = xr[tid];
        float ss = vv.x * vv.x + vv.y * vv.y + vv.z * vv.z + vv.w * vv.w;
        for (int off = 32; off > 0; off >>= 1) ss += __shfl_down(ss, off, 64);
        __shared__ float wsum[4];
        int lane = tid & 63, wv = tid >> 6;
        if (lane == 0) wsum[wv] = ss;
        __syncthreads();
        float nrm = sqrtf(wsum[0] + wsum[1] + wsum[2] + wsum[3]);
        float inv = 1.0f / fmaxf(nrm, 1e-12f);
        ushort4 o;
        o.x = f2bf(vv.x * inv); o.y = f2bf(vv.y * inv);
        o.z = f2bf(vv.z * inv); o.w = f2bf(vv.w * inv);
        *(ushort4*)(xn + (size_t)bid * D_MODEL + tid * 4) = o;
        if (tid == 0) { norms[bid] = nrm; cnt[bid] = 0; }
    } else {
        size_t i = (size_t)(bid - NROWS) * 256 + tid;   // float4 chunk index
        float4 w = ((const float4*)Wv)[i];
        ushort4 o;
        o.x = f2bf(w.x); o.y = f2bf(w.y); o.z = f2bf(w.z); o.w = f2bf(w.w);
        *(ushort4*)(Wvb + i * 4) = o;
    }
}

// ---------- L2: register-direct fused GEMM, NO LDS / NO BARRIERS ----------
// blocks 0..1023: vproj -> out directly; blocks 1024..2079: symmetric sim/count.
// 4 waves as 2x2; each wave a 32x32 micro-tile; fragments loaded straight from
// global (16B/lane, k-contiguous) so the K-loop has zero __syncthreads and the
// compiler pipelines loads across iterations with fine-grained vmcnt.
__global__ __launch_bounds__(256) void k_main(const unsigned short* __restrict__ xn,
                                              const unsigned short* __restrict__ Wvb,
                                              const float* __restrict__ bv,
                                              const float* __restrict__ norms,
                                              int* __restrict__ cnt,
                                              float* __restrict__ out) {
    int bid = blockIdx.x;
    int tid = threadIdx.x;
    int lane = tid & 63, wave = tid >> 6;
    int wm = wave & 1, wn = wave >> 1;
    int lrow = lane & 15, quad = lane >> 4;

    const unsigned short* Asrc;
    const unsigned short* Bsrc;
    int rowBase, colBase;
    bool isV;
    int b = 0, bi = 0, bj = 0;
    if (bid < VP_BLOCKS) {
        isV = true;
        rowBase = (bid >> 4) * TS;      // 64 row-blocks
        colBase = (bid & 15) * TS;      // 16 col-blocks
        Asrc = xn;
        Bsrc = Wvb;
    } else {
        isV = false;
        int sidx = bid - VP_BLOCKS;
        b = (sidx >= SIM_TRI) ? 1 : 0;
        int r = sidx - b * SIM_TRI;
        bi = 0;
        while (r >= SIM_ROWB - bi) { r -= SIM_ROWB - bi; ++bi; }
        bj = bi + r;
        rowBase = bi * TS;              // batch-local
        colBase = bj * TS;
        Asrc = xn + (size_t)b * SEQ * D_MODEL;
        Bsrc = Asrc;
    }

    // per-lane fragment base pointers (16B-aligned, k-contiguous)
    const unsigned short* Ab = Asrc + (size_t)(rowBase + wm * 32 + lrow) * D_MODEL + quad * 8;
    const unsigned short* Bb = Bsrc + (size_t)(colBase + wn * 32 + lrow) * D_MODEL + quad * 8;

    f32x4 acc[2][2] = {};
#pragma unroll 8
    for (int it = 0; it < D_MODEL / 32; ++it) {
        int ko = it * 32;
        bf16x8 av[2], bvv[2];
        av[0]  = *(const bf16x8*)(Ab + ko);
        av[1]  = *(const bf16x8*)(Ab + 16 * D_MODEL + ko);
        bvv[0] = *(const bf16x8*)(Bb + ko);
        bvv[1] = *(const bf16x8*)(Bb + 16 * D_MODEL + ko);
#pragma unroll
        for (int mt = 0; mt < 2; ++mt)
#pragma unroll
            for (int nt = 0; nt < 2; ++nt)
                acc[mt][nt] = __builtin_amdgcn_mfma_f32_16x16x32_bf16(av[mt], bvv[nt], acc[mt][nt], 0, 0, 0);
    }

    if (isV) {
#pragma unroll
        for (int mt = 0; mt < 2; ++mt) {
#pragma unroll
            for (int nt = 0; nt < 2; ++nt) {
                int n = colBase + wn * 32 + nt * 16 + lrow;
                float bn = bv[n];
                int h = n >> 6, j = n & 63;
#pragma unroll
                for (int r = 0; r < 4; ++r) {
                    int m = rowBase + wm * 32 + mt * 16 + quad * 4 + r;
                    float val = acc[mt][nt][r] * norms[m] + bn;
                    int bb = m >> 11, s = m & (SEQ - 1);
                    out[(((size_t)(bb * NUM_HEADS + h)) * SEQ + s) * D_K + j] = val;
                }
            }
        }
    } else {
        int* cb = cnt + b * SEQ;
        bool diag = (bi == bj);
#pragma unroll
        for (int mt = 0; mt < 2; ++mt) {
#pragma unroll
            for (int nt = 0; nt < 2; ++nt) {
                int n = colBase + wn * 32 + nt * 16 + lrow;
#pragma unroll
                for (int r = 0; r < 4; ++r) {
                    int m = rowBase + wm * 32 + mt * 16 + quad * 4 + r;
                    if (acc[mt][nt][r] > SIM_THRESH) {
                        atomicAdd(&cb[m], 1);
                        if (!diag) atomicAdd(&cb[n], 1);
                    }
                }
            }
        }
    }
}

// ---------- L3: fix rows with cnt != 1 (cold; cnt==1 rows already hold out = v row).
// Self-sufficient: recomputes mask row, q-row, k-rows AND v-rows on demand. ----------
__global__ __launch_bounds__(256) void k_fix(
    const float* __restrict__ x,
    const float* __restrict__ Wq, const float* __restrict__ bq,
    const float* __restrict__ Wk, const float* __restrict__ bk,
    const unsigned short* __restrict__ Wvb, const float* __restrict__ bvv,
    const unsigned short* __restrict__ xn,
    const float* __restrict__ norms,
    const int* __restrict__ cnt,
    float* __restrict__ out)
{
    int tid = threadIdx.x;
    int rowBase = blockIdx.x * 256;

    __shared__ int list[256];
    __shared__ int nlist;
    if (tid == 0) nlist = 0;
    __syncthreads();
    int grow = rowBase + tid;
    if (cnt[grow] != 1) { int p = atomicAdd(&nlist, 1); list[p] = grow; }
    __syncthreads();
    int nfix = nlist;
    if (nfix == 0) return;

    __shared__ uint8_t mrow[SEQ];
    __shared__ float q_row[D_MODEL];
    __shared__ float k_row[D_MODEL];
    __shared__ float v_row[D_MODEL];
    __shared__ float accO[D_MODEL];
    __shared__ float m_h[NUM_HEADS], l_h[NUM_HEADS], alpha_h[NUM_HEADS], p_h[NUM_HEADS];

    for (int li = 0; li < nfix; ++li) {
        int row = list[li];
        int b = row >> 11, s = row & (SEQ - 1);

        const unsigned short* xs = xn + (size_t)row * D_MODEL;
        for (int t = tid; t < SEQ; t += 256) {
            const unsigned short* xt = xn + ((size_t)b * SEQ + t) * D_MODEL;
            float d = 0.f;
            for (int k = 0; k < D_MODEL; ++k) d += bf2f(xs[k]) * bf2f(xt[k]);
            mrow[t] = (d > SIM_THRESH) ? 1 : 0;
        }

        const float* xrow = x + (size_t)row * D_MODEL;
        for (int c = tid; c < D_MODEL; c += 256) {
            const float* w = Wq + (size_t)c * D_MODEL;
            float acc = bq[c];
            for (int d = 0; d < D_MODEL; ++d) acc += xrow[d] * w[d];
            q_row[c] = acc;
            accO[c] = 0.f;
        }
        if (tid < NUM_HEADS) { m_h[tid] = -INFINITY; l_h[tid] = 0.f; }
        __syncthreads();

        for (int t = 0; t < SEQ; ++t) {
            if (!mrow[t]) continue;
            const float* xt = x + ((size_t)b * SEQ + t) * D_MODEL;
            const unsigned short* xnt = xn + ((size_t)b * SEQ + t) * D_MODEL;
            float nt = norms[b * SEQ + t];
            for (int c = tid; c < D_MODEL; c += 256) {
                const float* w = Wk + (size_t)c * D_MODEL;
                float acc = bk[c];
                for (int d = 0; d < D_MODEL; ++d) acc += xt[d] * w[d];
                k_row[c] = acc;
                const unsigned short* wv = Wvb + (size_t)c * D_MODEL;
                float av = 0.f;
                for (int d = 0; d < D_MODEL; ++d) av += bf2f(xnt[d]) * bf2f(wv[d]);
                v_row[c] = av * nt + bvv[c];
            }
            __syncthreads();
            if (tid < NUM_HEADS) {
                float sc = 0.f;
                for (int j = 0; j < D_K; ++j) sc += q_row[tid * D_K + j] * k_row[tid * D_K + j];
                sc *= 0.125f;
                float mnew = fmaxf(m_h[tid], sc);
                float alpha = expf(m_h[tid] - mnew);
                float p = expf(sc - mnew);
                l_h[tid] = l_h[tid] * alpha + p;
                m_h[tid] = mnew;
                alpha_h[tid] = alpha;
                p_h[tid] = p;
            }
            __syncthreads();
            for (int c = tid; c < D_MODEL; c += 256) {
                int h = c >> 6;
                accO[c] = accO[c] * alpha_h[h] + p_h[h] * v_row[c];
            }
            __syncthreads();
        }
        for (int c = tid; c < D_MODEL; c += 256) {
            int h = c >> 6, j = c & 63;
            out[(((size_t)(b * NUM_HEADS + h)) * SEQ + s) * D_K + j] = accO[c] / l_h[h];
        }
        __syncthreads();
    }
}

extern "C" void kernel_launch(void* const* d_in, const int* in_sizes, int n_in,
                              void* d_out, int out_size, void* d_ws, size_t ws_size,
                              hipStream_t stream) {
    const float* x  = (const float*)d_in[0];
    const float* Wq = (const float*)d_in[1];
    const float* bq = (const float*)d_in[2];
    const float* Wk = (const float*)d_in[3];
    const float* bk = (const float*)d_in[4];
    const float* Wv = (const float*)d_in[5];
    const float* bv = (const float*)d_in[6];
    float* out = (float*)d_out;

    // workspace: xn bf16 (8MB) | Wvb bf16 (2MB) | norms (16KB) | cnt (16KB)
    unsigned short* xn  = (unsigned short*)d_ws;
    unsigned short* Wvb = xn + (size_t)NROWS * D_MODEL;
    float* norms = (float*)(Wvb + (size_t)D_MODEL * D_MODEL);
    int* cnt     = (int*)(norms + NROWS);

    // L1: 4096 row-normalize blocks + 1024 Wv-cast blocks
    k_prep<<<NROWS + D_MODEL * D_MODEL / 1024, 256, 0, stream>>>(x, Wv, xn, Wvb, norms, cnt);

    // L2: 1024 vproj blocks + 1056 sim blocks, register-direct, no barriers
    k_main<<<GRID, 256, 0, stream>>>(xn, Wvb, bv, norms, cnt, out);

    // L3: fix non-singleton rows (cold)
    k_fix<<<NROWS / 256, 256, 0, stream>>>(x, Wq, bq, Wk, bk, Wvb, bv, xn, norms, cnt, out);
}

// Round 8
// 151.009 us; speedup vs baseline: 1.4075x; 1.4075x over previous
//
#include <hip/hip_runtime.h>
#include <stdint.h>
#include <math.h>

#define D_MODEL 1024
#define NUM_HEADS 16
#define D_K 64
#define SEQ 2048
#define BATCH 2
#define SIM_THRESH 0.7f

#define TS 64          // block tile (square)
#define BKK 128        // K chunk per barrier
#define NITK (D_MODEL / BKK)   // 8 barriers per block

#define NROWS (BATCH * SEQ)                       // 4096
#define VP_BLOCKS ((NROWS / TS) * (D_MODEL / TS)) // 64*16 = 1024
#define SIM_ROWB (SEQ / TS)                       // 32
#define SIM_TRI (SIM_ROWB * (SIM_ROWB + 1) / 2)   // 528
#define SIM_BLOCKS (SIM_TRI * BATCH)              // 1056
#define GRID (VP_BLOCKS + SIM_BLOCKS)             // 2080

#define TILE_SH (TS * BKK)   // 8192 shorts = 16 KB per tile

typedef __attribute__((ext_vector_type(8))) short bf16x8;
typedef __attribute__((ext_vector_type(4))) float f32x4;

static __device__ __forceinline__ unsigned short f2bf(float f) {
    unsigned int u = __float_as_uint(f);
    unsigned int r = (u + 0x7FFF + ((u >> 16) & 1)) >> 16;   // RNE
    return (unsigned short)r;
}
static __device__ __forceinline__ float bf2f(unsigned short u) {
    return __uint_as_float(((unsigned int)u) << 16);
}

// ---------- L1: normalize x rows -> bf16 (+norms, zero cnt); cast Wv -> bf16 ----------
// wave-per-row (no intra-block syncs); 1024 row-blocks + 1024 Wv-cast blocks
__global__ __launch_bounds__(256) void k_prep(const float* __restrict__ x,
                                              const float* __restrict__ Wv,
                                              unsigned short* __restrict__ xn,
                                              unsigned short* __restrict__ Wvb,
                                              float* __restrict__ norms,
                                              int* __restrict__ cnt) {
    int bid = blockIdx.x, tid = threadIdx.x;
    int lane = tid & 63, wv = tid >> 6;
    if (bid < NROWS / 4) {
        int row = bid * 4 + wv;
        const float4* xr = (const float4*)(x + (size_t)row * D_MODEL);
        float4 vv[4];
        float ss = 0.f;
#pragma unroll
        for (int i = 0; i < 4; ++i) {
            vv[i] = xr[lane + i * 64];
            ss += vv[i].x * vv[i].x + vv[i].y * vv[i].y + vv[i].z * vv[i].z + vv[i].w * vv[i].w;
        }
        for (int off = 32; off > 0; off >>= 1) ss += __shfl_down(ss, off, 64);
        float nrm = sqrtf(__shfl(ss, 0, 64));
        float inv = 1.0f / fmaxf(nrm, 1e-12f);
#pragma unroll
        for (int i = 0; i < 4; ++i) {
            ushort4 o;
            o.x = f2bf(vv[i].x * inv); o.y = f2bf(vv[i].y * inv);
            o.z = f2bf(vv[i].z * inv); o.w = f2bf(vv[i].w * inv);
            *(ushort4*)(xn + (size_t)row * D_MODEL + (lane + i * 64) * 4) = o;
        }
        if (lane == 0) { norms[row] = nrm; cnt[row] = 0; }
    } else {
        size_t i = (size_t)(bid - NROWS / 4) * 256 + tid;   // float4 chunk index
        float4 w = ((const float4*)Wv)[i];
        ushort4 o;
        o.x = f2bf(w.x); o.y = f2bf(w.y); o.z = f2bf(w.z); o.w = f2bf(w.w);
        *(ushort4*)(Wvb + i * 4) = o;
    }
}

// ---------- staging: 64x128 bf16 tile, FRAGMENT-MAJOR LDS layout ----------
// LDS chunk c (16B) holds A[row = g*16 + (l&15)][k = kb*32 + (l>>4)*8 ..+8)
// where l = c&63, kb = (c>>6)&3, g = c>>8. ds_read of fragment (g,kb) by the
// 64 lanes then covers 64 consecutive chunks -> conflict-free by construction.
static __device__ __forceinline__ void stage_fm(const unsigned short* __restrict__ gsrc,
                                                int rowBase, int kk,
                                                short* lds, int tid) {
#pragma unroll
    for (int p = 0; p < 4; ++p) {
        int c = p * 256 + tid;
        int l = c & 63, kb = (c >> 6) & 3, g = c >> 8;
        const unsigned short* ga = gsrc + (size_t)(rowBase + g * 16 + (l & 15)) * D_MODEL
                                        + kk + kb * 32 + (l >> 4) * 8;
        __builtin_amdgcn_global_load_lds(
            (const __attribute__((address_space(1))) unsigned int*)ga,
            (__attribute__((address_space(3))) unsigned int*)(lds + c * 8),
            16, 0, 0);
    }
}

// ---------- L2: fused V-proj (blocks 0..1023) + symmetric sim/count (1024..2079) ----------
// 64x64 tiles, BK=128 single-buffered (8 barriers/block), fragment-major LDS.
__global__ __launch_bounds__(256) void k_main(const unsigned short* __restrict__ xn,
                                              const unsigned short* __restrict__ Wvb,
                                              const float* __restrict__ bv,
                                              const float* __restrict__ norms,
                                              int* __restrict__ cnt,
                                              float* __restrict__ out) {
    __shared__ short As[TILE_SH];
    __shared__ short Bs[TILE_SH];
    int bid = blockIdx.x;
    int tid = threadIdx.x;
    int lane = tid & 63, wave = tid >> 6;
    int wm = wave & 1, wn = wave >> 1;
    int lrow = lane & 15, quad = lane >> 4;

    const unsigned short* Asrc;
    const unsigned short* Bsrc;
    int rowBase, colBase;
    bool isV;
    int b = 0, bi = 0, bj = 0;
    if (bid < VP_BLOCKS) {
        isV = true;
        rowBase = (bid >> 4) * TS;
        colBase = (bid & 15) * TS;
        Asrc = xn;
        Bsrc = Wvb;
    } else {
        isV = false;
        int sidx = bid - VP_BLOCKS;
        b = (sidx >= SIM_TRI) ? 1 : 0;
        int r = sidx - b * SIM_TRI;
        bi = 0;
        while (r >= SIM_ROWB - bi) { r -= SIM_ROWB - bi; ++bi; }
        bj = bi + r;
        rowBase = bi * TS;              // batch-local
        colBase = bj * TS;
        Asrc = xn + (size_t)b * SEQ * D_MODEL;
        Bsrc = Asrc;
    }
    bool aliasB = (!isV) && (bi == bj);          // diagonal sim block: B tile == A tile
    const short* Bsp = aliasB ? As : Bs;

    f32x4 acc[2][2] = {};
    for (int it = 0; it < NITK; ++it) {
        stage_fm(Asrc, rowBase, it * BKK, As, tid);
        if (!aliasB) stage_fm(Bsrc, colBase, it * BKK, Bs, tid);
        __syncthreads();
#pragma unroll
        for (int kb = 0; kb < 4; ++kb) {
            bf16x8 av[2], bvv[2];
#pragma unroll
            for (int mt = 0; mt < 2; ++mt)
                av[mt] = *(const bf16x8*)(As + (((wm * 2 + mt) * 4 + kb) * 64 + lane) * 8);
#pragma unroll
            for (int nt = 0; nt < 2; ++nt)
                bvv[nt] = *(const bf16x8*)(Bsp + (((wn * 2 + nt) * 4 + kb) * 64 + lane) * 8);
#pragma unroll
            for (int mt = 0; mt < 2; ++mt)
#pragma unroll
                for (int nt = 0; nt < 2; ++nt)
                    acc[mt][nt] = __builtin_amdgcn_mfma_f32_16x16x32_bf16(av[mt], bvv[nt], acc[mt][nt], 0, 0, 0);
        }
        __syncthreads();
    }

    if (isV) {
#pragma unroll
        for (int mt = 0; mt < 2; ++mt) {
#pragma unroll
            for (int nt = 0; nt < 2; ++nt) {
                int n = colBase + wn * 32 + nt * 16 + lrow;
                float bn = bv[n];
                int h = n >> 6, j = n & 63;
#pragma unroll
                for (int r = 0; r < 4; ++r) {
                    int m = rowBase + wm * 32 + mt * 16 + quad * 4 + r;
                    float val = acc[mt][nt][r] * norms[m] + bn;
                    int bb = m >> 11, s = m & (SEQ - 1);
                    out[(((size_t)(bb * NUM_HEADS + h)) * SEQ + s) * D_K + j] = val;
                }
            }
        }
    } else {
        int* cb = cnt + b * SEQ;
        bool diag = (bi == bj);
#pragma unroll
        for (int mt = 0; mt < 2; ++mt) {
#pragma unroll
            for (int nt = 0; nt < 2; ++nt) {
                int n = colBase + wn * 32 + nt * 16 + lrow;
#pragma unroll
                for (int r = 0; r < 4; ++r) {
                    int m = rowBase + wm * 32 + mt * 16 + quad * 4 + r;
                    if (acc[mt][nt][r] > SIM_THRESH) {
                        atomicAdd(&cb[m], 1);
                        if (!diag) atomicAdd(&cb[n], 1);
                    }
                }
            }
        }
    }
}

// ---------- L3: fix rows with cnt != 1 (cold; cnt==1 rows already hold out = v row).
// Self-sufficient: recomputes mask row, q-row, k-rows AND v-rows on demand. ----------
__global__ __launch_bounds__(256) void k_fix(
    const float* __restrict__ x,
    const float* __restrict__ Wq, const float* __restrict__ bq,
    const float* __restrict__ Wk, const float* __restrict__ bk,
    const unsigned short* __restrict__ Wvb, const float* __restrict__ bvv,
    const unsigned short* __restrict__ xn,
    const float* __restrict__ norms,
    const int* __restrict__ cnt,
    float* __restrict__ out)
{
    int tid = threadIdx.x;
    int rowBase = blockIdx.x * 256;

    __shared__ int list[256];
    __shared__ int nlist;
    if (tid == 0) nlist = 0;
    __syncthreads();
    int grow = rowBase + tid;
    if (cnt[grow] != 1) { int p = atomicAdd(&nlist, 1); list[p] = grow; }
    __syncthreads();
    int nfix = nlist;
    if (nfix == 0) return;

    __shared__ uint8_t mrow[SEQ];
    __shared__ float q_row[D_MODEL];
    __shared__ float k_row[D_MODEL];
    __shared__ float v_row[D_MODEL];
    __shared__ float accO[D_MODEL];
    __shared__ float m_h[NUM_HEADS], l_h[NUM_HEADS], alpha_h[NUM_HEADS], p_h[NUM_HEADS];

    for (int li = 0; li < nfix; ++li) {
        int row = list[li];
        int b = row >> 11, s = row & (SEQ - 1);

        const unsigned short* xs = xn + (size_t)row * D_MODEL;
        for (int t = tid; t < SEQ; t += 256) {
            const unsigned short* xt = xn + ((size_t)b * SEQ + t) * D_MODEL;
            float d = 0.f;
            for (int k = 0; k < D_MODEL; ++k) d += bf2f(xs[k]) * bf2f(xt[k]);
            mrow[t] = (d > SIM_THRESH) ? 1 : 0;
        }

        const float* xrow = x + (size_t)row * D_MODEL;
        for (int c = tid; c < D_MODEL; c += 256) {
            const float* w = Wq + (size_t)c * D_MODEL;
            float acc = bq[c];
            for (int d = 0; d < D_MODEL; ++d) acc += xrow[d] * w[d];
            q_row[c] = acc;
            accO[c] = 0.f;
        }
        if (tid < NUM_HEADS) { m_h[tid] = -INFINITY; l_h[tid] = 0.f; }
        __syncthreads();

        for (int t = 0; t < SEQ; ++t) {
            if (!mrow[t]) continue;
            const float* xt = x + ((size_t)b * SEQ + t) * D_MODEL;
            const unsigned short* xnt = xn + ((size_t)b * SEQ + t) * D_MODEL;
            float nt = norms[b * SEQ + t];
            for (int c = tid; c < D_MODEL; c += 256) {
                const float* w = Wk + (size_t)c * D_MODEL;
                float acc = bk[c];
                for (int d = 0; d < D_MODEL; ++d) acc += xt[d] * w[d];
                k_row[c] = acc;
                const unsigned short* wv = Wvb + (size_t)c * D_MODEL;
                float av = 0.f;
                for (int d = 0; d < D_MODEL; ++d) av += bf2f(xnt[d]) * bf2f(wv[d]);
                v_row[c] = av * nt + bvv[c];
            }
            __syncthreads();
            if (tid < NUM_HEADS) {
                float sc = 0.f;
                for (int j = 0; j < D_K; ++j) sc += q_row[tid * D_K + j] * k_row[tid * D_K + j];
                sc *= 0.125f;
                float mnew = fmaxf(m_h[tid], sc);
                float alpha = expf(m_h[tid] - mnew);
                float p = expf(sc - mnew);
                l_h[tid] = l_h[tid] * alpha + p;
                m_h[tid] = mnew;
                alpha_h[tid] = alpha;
                p_h[tid] = p;
            }
            __syncthreads();
            for (int c = tid; c < D_MODEL; c += 256) {
                int h = c >> 6;
                accO[c] = accO[c] * alpha_h[h] + p_h[h] * v_row[c];
            }
            __syncthreads();
        }
        for (int c = tid; c < D_MODEL; c += 256) {
            int h = c >> 6, j = c & 63;
            out[(((size_t)(b * NUM_HEADS + h)) * SEQ + s) * D_K + j] = accO[c] / l_h[h];
        }
        __syncthreads();
    }
}

extern "C" void kernel_launch(void* const* d_in, const int* in_sizes, int n_in,
                              void* d_out, int out_size, void* d_ws, size_t ws_size,
                              hipStream_t stream) {
    const float* x  = (const float*)d_in[0];
    const float* Wq = (const float*)d_in[1];
    const float* bq = (const float*)d_in[2];
    const float* Wk = (const float*)d_in[3];
    const float* bk = (const float*)d_in[4];
    const float* Wv = (const float*)d_in[5];
    const float* bv = (const float*)d_in[6];
    float* out = (float*)d_out;

    // workspace: xn bf16 (8MB) | Wvb bf16 (2MB) | norms (16KB) | cnt (16KB)
    unsigned short* xn  = (unsigned short*)d_ws;
    unsigned short* Wvb = xn + (size_t)NROWS * D_MODEL;
    float* norms = (float*)(Wvb + (size_t)D_MODEL * D_MODEL);
    int* cnt     = (int*)(norms + NROWS);

    // L1: 1024 row-blocks (wave-per-row) + 1024 Wv-cast blocks
    k_prep<<<NROWS / 4 + D_MODEL * D_MODEL / 1024, 256, 0, stream>>>(x, Wv, xn, Wvb, norms, cnt);

    // L2: 1024 vproj blocks + 1056 sim blocks; BK=128, 8 barriers/block
    k_main<<<GRID, 256, 0, stream>>>(xn, Wvb, bv, norms, cnt, out);

    // L3: fix non-singleton rows (cold)
    k_fix<<<NROWS / 256, 256, 0, stream>>>(x, Wq, bq, Wk, bk, Wvb, bv, xn, norms, cnt, out);
}